// Round 1
// baseline (124.170 us; speedup 1.0000x reference)
//
#include <hip/hip_runtime.h>
#include <hip/hip_fp16.h>
#include <math.h>

// Problem constants
#define NB 392      // n = b*oh*ow = 2*14*14
#define NI 288      // K*K*B = 9*32
#define NC 32       // C
#define NQ 16       // PSIZE
#define CQ 512      // NC*NQ
#define CH 544      // B*(PSIZE+1)
#define EPSV 1e-6f

// votes are fp8 e4m3 scaled by 32; routing descales algebraically.
#define VSCALE 32.0f
#define VINV (1.0f / 32.0f)

// out layout (floats)
#define OFF_AOUT 200704       // NB*CQ
#define OFF_CAT  213248       // OFF_AOUT + NB*NC

#define RT_THREADS 512

typedef _Float16 v4h __attribute__((ext_vector_type(4)));
typedef float v4f __attribute__((ext_vector_type(4)));
typedef float v2f __attribute__((ext_vector_type(2)));

// ---------------------------------------------------------------------------
// Gather from x via the unfold channel-major reinterpret.
__device__ __forceinline__ float gather_x(const float* __restrict__ x, int n, int j) {
    int c_idx = j / 9;
    int rem = j - c_idx * 9;
    int ki = rem / 3;
    int kj = rem - ki * 3;
    int b_ = n / 196;
    int rest = n - b_ * 196;
    int yy = rest / 14;
    int xx = rest - yy * 14;
    int iy = yy + ki - 1;
    int ix = xx + kj - 1;
    float v = 0.f;
    if ((unsigned)iy < 14u && (unsigned)ix < 14u)
        v = x[((b_ * 14 + iy) * 14 + ix) * CH + c_idx];
    return v;
}

// ---------------------------------------------------------------------------
// votes via swapped-operand mfma 16x16x16 f16, reading wts DIRECTLY.
// (unchanged from previous round — it is near its write-BW floor)
__global__ __launch_bounds__(256) void votes_k(const float* __restrict__ x,
                                               const float* __restrict__ wts,
                                               uchar* __restrict__ votes) {
    __shared__ uint tile[64 * 36];      // 9 KB, pitch 36 dwords (144 B)
    int mtt = blockIdx.x;         // 0..6
    int i = blockIdx.y;           // 0..287
    int t = threadIdx.x;
    int wv = t >> 6;
    int l = t & 63;
    int col = l & 15;
    int quad = l >> 4;

    // A-side p-frag: gather 4 p-values from x in-lane (n_row = col-mapped)
    int n_row = mtt * 64 + wv * 16 + col;
    v4h av = {};
    if (n_row < NB) {
        int jb = (i >> 5) * CH + (i & 31) * 16 + quad * 4;
#pragma unroll
        for (int kk = 0; kk < 4; ++kk)
            av[kk] = (_Float16)gather_x(x, n_row, jb + kk);
    }

    const float* wb = wts + (size_t)i * 8192 + quad * 64 + col;
    const uchar* tileb = (const uchar*)tile;

    for (int ch = 0; ch < 4; ++ch) {
#pragma unroll
        for (int c8 = 0; c8 < 8; ++c8) {
            int ct = ch * 8 + c8;
            const float* wp = wb + ct * 256;
            v4h bv;
            bv[0] = (_Float16)wp[0];
            bv[1] = (_Float16)wp[16];
            bv[2] = (_Float16)wp[32];
            bv[3] = (_Float16)wp[48];
            v4f acc = {0.f, 0.f, 0.f, 0.f};
            acc = __builtin_amdgcn_mfma_f32_16x16x16f16(bv, av, acc, 0, 0, 0);
            // lane holds votes[n=...+col][cq = ct*16 + quad*4 + 0..3]
            uint u = __builtin_amdgcn_cvt_pk_fp8_f32(acc[0] * VSCALE, acc[1] * VSCALE, 0, false);
            u = __builtin_amdgcn_cvt_pk_fp8_f32(acc[2] * VSCALE, acc[3] * VSCALE, u, true);
            tile[(wv * 16 + col) * 36 + c8 * 4 + quad] = u;
        }
        __syncthreads();
        // 64 rows x 8 uint4 = 512 uint4; 2 steps; 8 lanes store a row's 128 B.
#pragma unroll
        for (int k = 0; k < 2; ++k) {
            int idx = k * 256 + t;
            int row = idx >> 3;
            int off = idx & 7;
            int n_out = mtt * 64 + row;
            if (n_out < NB) {
                uint4 d = *(const uint4*)&tileb[row * 144 + off * 16];
                *(uint4*)(votes + (((size_t)n_out * NI + i) << 9) + ch * 128 + off * 16) = d;
            }
        }
        __syncthreads();
    }
}

// ---------------------------------------------------------------------------
// Fused dynamic routing. Block = n, 512 threads (8 waves).
// NEW: the 144 KB per-n fp8 vote slice is stashed into LDS during iter 0's
// single global streaming pass; iters 1-2 read votes from LDS (ds_read_b128,
// 2-way bank alias only -> free). Cuts global vote traffic 3x -> 1x and
// removes global-load latency from iters 1-2.
// To fit LDS (<=160 KiB/CU): the 8-slot partial-sum buffer becomes a 2-stage
// tree over 4 slots (8 KB): waves 0-3 write, waves 4-7 accumulate in place,
// then 512-thread fold over 4 slots.
// LDS total: 147456 (votes) + 8192 (sred) + 2048 (vj) + 1152 (afs) + 128 = 158976 B
// -> 1 block/CU, 2 waves/SIMD.
__global__ __launch_bounds__(RT_THREADS) void routing_k(const uchar* __restrict__ votes,
                                                        const float* __restrict__ x,
                                                        float* __restrict__ out) {
    __shared__ uint4 vlds4[NI * 32];     // 144 KB fp8 votes for this n
    __shared__ float sred[4 * CQ];       // 8 KB, [slot][q*32+c]
    __shared__ float vj[CQ];             // [q*32+c]
    __shared__ float afs[NI];
    __shared__ float aout_s[NC];

    int n = blockIdx.x;
    int t = threadIdx.x;
    int wv = t >> 6;      // 0..7
    int l = t & 63;
    int c = l & 31;
    int g = l >> 5;

    if (t < NI) {
        int j = (t >> 5) * CH + 512 + (t & 31);
        float v = gather_x(x, n, j);
        float a = fminf(fmaxf(v, 1e-4f), 1.0f);
        afs[t] = a / (a + EPSV);
    }
    __syncthreads();

    const uchar* vb = votes + (size_t)n * NI * 512;
    float vjr[16];    // cumulative vj, PRE-SCALED by 1/32
    float sreg[16];

#define VROW(S) (((const uint4*)(vb + ((size_t)(((((S) << 3) + wv) << 1) + g) << 9)))[c])

#define DECODE(CUR, VT) { v2f p_; \
    p_ = __builtin_amdgcn_cvt_pk_f32_fp8(CUR.x, false); VT[0] = p_[0];  VT[1] = p_[1]; \
    p_ = __builtin_amdgcn_cvt_pk_f32_fp8(CUR.x, true);  VT[2] = p_[0];  VT[3] = p_[1]; \
    p_ = __builtin_amdgcn_cvt_pk_f32_fp8(CUR.y, false); VT[4] = p_[0];  VT[5] = p_[1]; \
    p_ = __builtin_amdgcn_cvt_pk_f32_fp8(CUR.y, true);  VT[6] = p_[0];  VT[7] = p_[1]; \
    p_ = __builtin_amdgcn_cvt_pk_f32_fp8(CUR.z, false); VT[8] = p_[0];  VT[9] = p_[1]; \
    p_ = __builtin_amdgcn_cvt_pk_f32_fp8(CUR.z, true);  VT[10] = p_[0]; VT[11] = p_[1]; \
    p_ = __builtin_amdgcn_cvt_pk_f32_fp8(CUR.w, false); VT[12] = p_[0]; VT[13] = p_[1]; \
    p_ = __builtin_amdgcn_cvt_pk_f32_fp8(CUR.w, true);  VT[14] = p_[0]; VT[15] = p_[1]; }

    // Shared reduction + squash + vjr update (uniform control flow).
    auto reduce_squash = [&](int iter) {
        // fold g-halves
#pragma unroll
        for (int q = 0; q < 16; ++q) sreg[q] += __shfl_xor(sreg[q], 32);
        // stage 1: waves 0-3 write their partials (layout [q*32+c]: bank==c)
        if (g == 0 && wv < 4) {
            float* sw = &sred[wv * CQ + c];
#pragma unroll
            for (int q = 0; q < 16; ++q) sw[q * 32] = sreg[q];
        }
        __syncthreads();
        // stage 2: waves 4-7 accumulate into slot wv-4 in place
        if (g == 0 && wv >= 4) {
            float* sw = &sred[(wv - 4) * CQ + c];
#pragma unroll
            for (int q = 0; q < 16; ++q) sw[q * 32] += sreg[q];
        }
        __syncthreads();
        {
            float ssum = 0.f;   // 512 threads == CQ columns
#pragma unroll
            for (int k = 0; k < 4; ++k) ssum += sred[k * CQ + t];
            sred[t] = ssum * VINV;   // descale the x32 fp8 encoding ONCE
        }
        __syncthreads();

        // squash (threads 0..31, one c each; element (c,q) at sred[q*32+c])
        if (t < NC) {
            float s2 = 0.f;
#pragma unroll
            for (int q = 0; q < 16; ++q) {
                float s = sred[q * 32 + t];
                s2 += s * s;
            }
            float f = (s2 / (1.f + s2)) / sqrtf(s2 + EPSV);
            float vn2 = 0.f;
#pragma unroll
            for (int q = 0; q < 16; ++q) {
                float v = f * sred[q * 32 + t];
                vj[q * 32 + t] = v;
                vn2 += v * v;
            }
            if (iter == 2) {
                float ao = sqrtf(vn2 + EPSV);
                ao = fminf(fmaxf(ao, 1e-4f), 1.f - 1e-4f);
                aout_s[t] = ao;
            }
        }
        __syncthreads();
        if (iter < 2) {
#pragma unroll
            for (int q = 0; q < 16; ++q) {
                float v = vj[q * 32 + c] * VINV;   // pre-scale for the raw dot
                vjr[q] = (iter == 0) ? v : vjr[q] + v;
            }
        }
    };

    // -------- iter 0: single global streaming pass + LDS stash --------
    {
#pragma unroll
        for (int q = 0; q < 16; ++q) sreg[q] = 0.f;

        uint4 f0 = VROW(0), f1 = VROW(1), f2 = VROW(2), f3 = VROW(3);

#pragma clang loop unroll_count(2)
        for (int s = 0; s < 18; ++s) {
            int i = (s << 4) + (wv << 1) + g;
            uint4 cur = f0;
            f0 = f1; f1 = f2; f2 = f3;
            if (s + 4 < 18) f3 = VROW(s + 4);

            vlds4[i * 32 + c] = cur;    // stash for iters 1-2 (ds_write_b128)

            float vt[16];   // raw fp8-decoded (x32-scaled votes)
            DECODE(cur, vt);
            float cij = afs[i] * (1.0f / 32.0f);
#pragma unroll
            for (int q = 0; q < 16; ++q) sreg[q] += cij * vt[q];
        }
        reduce_squash(0);
    }

    // -------- iters 1,2: votes from LDS --------
    for (int iter = 1; iter < 3; ++iter) {
#pragma unroll
        for (int q = 0; q < 16; ++q) sreg[q] = 0.f;

#pragma clang loop unroll_count(2)
        for (int s = 0; s < 18; ++s) {
            int i = (s << 4) + (wv << 1) + g;
            uint4 cur = vlds4[i * 32 + c];     // ds_read_b128, conflict-free

            float vt[16];
            DECODE(cur, vt);

            float ah = 0.f;   // vt(raw) . vjr(pre-scaled) == true dot
#pragma unroll
            for (int q = 0; q < 16; ++q) ah += vt[q] * vjr[q];
            float e = __expf(ah);
            float ssum = e;
            ssum += __shfl_xor(ssum, 1);
            ssum += __shfl_xor(ssum, 2);
            ssum += __shfl_xor(ssum, 4);
            ssum += __shfl_xor(ssum, 8);
            ssum += __shfl_xor(ssum, 16);
            float cij = e * __builtin_amdgcn_rcpf(ssum) * afs[i];
#pragma unroll
            for (int q = 0; q < 16; ++q) sreg[q] += cij * vt[q];
        }
        reduce_squash(iter);
    }

    // outputs: p_out, a_out, concat(out).  canonical idx t: c=t>>4, q=t&15
    {
        float v = vj[(t & 15) * 32 + (t >> 4)];
        out[(size_t)n * CQ + t] = v;
        out[OFF_CAT + (size_t)n * 544 + t] = v;
    }
    if (t < NC) {
        float ao = aout_s[t];
        out[OFF_AOUT + n * 32 + t] = ao;
        out[OFF_CAT + (size_t)n * 544 + 512 + t] = ao;
    }
}

// ---------------------------------------------------------------------------
extern "C" void kernel_launch(void* const* d_in, const int* in_sizes, int n_in,
                              void* d_out, int out_size, void* d_ws, size_t ws_size,
                              hipStream_t stream) {
    const float* x = (const float*)d_in[0];
    const float* wts = (const float*)d_in[1];
    float* out = (float*)d_out;
    uchar* votes = (uchar*)d_ws;   // 57.8 MB fp8

    hipLaunchKernelGGL(votes_k, dim3(7, NI), dim3(256), 0, stream,
                       x, wts, votes);
    hipLaunchKernelGGL(routing_k, dim3(NB), dim3(RT_THREADS), 0, stream,
                       votes, x, out);
}

// Round 2
// 117.105 us; speedup vs baseline: 1.0603x; 1.0603x over previous
//
#include <hip/hip_runtime.h>
#include <hip/hip_fp16.h>
#include <math.h>

// Problem constants
#define NB 392      // n = b*oh*ow = 2*14*14
#define NI 288      // K*K*B = 9*32
#define NC 32       // C
#define NQ 16       // PSIZE
#define CQ 512      // NC*NQ
#define CH 544      // B*(PSIZE+1)
#define EPSV 1e-6f

// votes are fp8 e4m3 scaled by 32; routing descales algebraically.
#define VSCALE 32.0f
#define VINV (1.0f / 32.0f)

// out layout (floats)
#define OFF_AOUT 200704       // NB*CQ
#define OFF_CAT  213248       // OFF_AOUT + NB*NC

// routing: 1024 threads = 16 waves; i split 32-way -> 9 serial steps/iter.
#define RT_THREADS 1024
#define RT_WAVES 16

typedef _Float16 v4h __attribute__((ext_vector_type(4)));
typedef float v4f __attribute__((ext_vector_type(4)));
typedef float v2f __attribute__((ext_vector_type(2)));

// ---------------------------------------------------------------------------
// Gather from x via the unfold channel-major reinterpret.
__device__ __forceinline__ float gather_x(const float* __restrict__ x, int n, int j) {
    int c_idx = j / 9;
    int rem = j - c_idx * 9;
    int ki = rem / 3;
    int kj = rem - ki * 3;
    int b_ = n / 196;
    int rest = n - b_ * 196;
    int yy = rest / 14;
    int xx = rest - yy * 14;
    int iy = yy + ki - 1;
    int ix = xx + kj - 1;
    float v = 0.f;
    if ((unsigned)iy < 14u && (unsigned)ix < 14u)
        v = x[((b_ * 14 + iy) * 14 + ix) * CH + c_idx];
    return v;
}

// ---------------------------------------------------------------------------
// votes via swapped-operand mfma 16x16x16 f16, reading wts DIRECTLY.
// (unchanged — single-variable A/B: this round only touches routing_k)
__global__ __launch_bounds__(256) void votes_k(const float* __restrict__ x,
                                               const float* __restrict__ wts,
                                               uchar* __restrict__ votes) {
    __shared__ uint tile[64 * 36];      // 9 KB, pitch 36 dwords (144 B)
    int mtt = blockIdx.x;         // 0..6
    int i = blockIdx.y;           // 0..287
    int t = threadIdx.x;
    int wv = t >> 6;
    int l = t & 63;
    int col = l & 15;
    int quad = l >> 4;

    // A-side p-frag: gather 4 p-values from x in-lane (n_row = col-mapped)
    int n_row = mtt * 64 + wv * 16 + col;
    v4h av = {};
    if (n_row < NB) {
        int jb = (i >> 5) * CH + (i & 31) * 16 + quad * 4;
#pragma unroll
        for (int kk = 0; kk < 4; ++kk)
            av[kk] = (_Float16)gather_x(x, n_row, jb + kk);
    }

    const float* wb = wts + (size_t)i * 8192 + quad * 64 + col;
    const uchar* tileb = (const uchar*)tile;

    for (int ch = 0; ch < 4; ++ch) {
#pragma unroll
        for (int c8 = 0; c8 < 8; ++c8) {
            int ct = ch * 8 + c8;
            const float* wp = wb + ct * 256;
            v4h bv;
            bv[0] = (_Float16)wp[0];
            bv[1] = (_Float16)wp[16];
            bv[2] = (_Float16)wp[32];
            bv[3] = (_Float16)wp[48];
            v4f acc = {0.f, 0.f, 0.f, 0.f};
            acc = __builtin_amdgcn_mfma_f32_16x16x16f16(bv, av, acc, 0, 0, 0);
            // lane holds votes[n=...+col][cq = ct*16 + quad*4 + 0..3]
            uint u = __builtin_amdgcn_cvt_pk_fp8_f32(acc[0] * VSCALE, acc[1] * VSCALE, 0, false);
            u = __builtin_amdgcn_cvt_pk_fp8_f32(acc[2] * VSCALE, acc[3] * VSCALE, u, true);
            tile[(wv * 16 + col) * 36 + c8 * 4 + quad] = u;
        }
        __syncthreads();
        // 64 rows x 8 uint4 = 512 uint4; 2 steps; 8 lanes store a row's 128 B.
#pragma unroll
        for (int k = 0; k < 2; ++k) {
            int idx = k * 256 + t;
            int row = idx >> 3;
            int off = idx & 7;
            int n_out = mtt * 64 + row;
            if (n_out < NB) {
                uint4 d = *(const uint4*)&tileb[row * 144 + off * 16];
                *(uint4*)(votes + (((size_t)n_out * NI + i) << 9) + ch * 128 + off * 16) = d;
            }
        }
        __syncthreads();
    }
}

// ---------------------------------------------------------------------------
// Fused dynamic routing. Block = n, 1024 threads (16 waves).
// Round-1 post-mortem: routing is LATENCY-bound (votes are L3-resident, so the
// 3x global streaming is cheap; the LDS stash only cut occupancy and lost 9us).
// This round: i split 32-way (group = wv*2+g over 16 waves) -> 9 serial steps
// per iter (was 18), 4 waves/SIMD guaranteed per block (was ~2-3). Depth-4
// prefetch over 9 steps now covers ~4*4*112 cyc >> L3 latency -> load stalls
// hidden by TLP. __launch_bounds__(1024) caps VGPR at 128 (live set ~75).
// sred: 16 slots x 2 KB = 32 KB LDS (not occupancy-binding).
__global__ __launch_bounds__(RT_THREADS) void routing_k(const uchar* __restrict__ votes,
                                                        const float* __restrict__ x,
                                                        float* __restrict__ out) {
    __shared__ float sred[RT_WAVES * CQ];   // 32 KB, [slot][q*32+c]
    __shared__ float vj[CQ];                // [q*32+c]
    __shared__ float afs[NI];
    __shared__ float aout_s[NC];

    int n = blockIdx.x;
    int t = threadIdx.x;
    int wv = t >> 6;      // 0..15
    int l = t & 63;
    int c = l & 31;
    int g = l >> 5;
    int grp = (wv << 1) | g;   // 0..31, i-group

    if (t < NI) {
        int j = (t >> 5) * CH + 512 + (t & 31);
        float v = gather_x(x, n, j);
        float a = fminf(fmaxf(v, 1e-4f), 1.0f);
        afs[t] = a / (a + EPSV);
    }
    __syncthreads();

    const uchar* vb = votes + (size_t)n * NI * 512;
    float vjr[16];    // cumulative vj, PRE-SCALED by 1/32
    float sreg[16];

#define VROW(S) (((const uint4*)(vb + ((size_t)(((S) << 5) + grp) << 9)))[c])

#define DECODE(CUR, VT) { v2f p_; \
    p_ = __builtin_amdgcn_cvt_pk_f32_fp8(CUR.x, false); VT[0] = p_[0];  VT[1] = p_[1]; \
    p_ = __builtin_amdgcn_cvt_pk_f32_fp8(CUR.x, true);  VT[2] = p_[0];  VT[3] = p_[1]; \
    p_ = __builtin_amdgcn_cvt_pk_f32_fp8(CUR.y, false); VT[4] = p_[0];  VT[5] = p_[1]; \
    p_ = __builtin_amdgcn_cvt_pk_f32_fp8(CUR.y, true);  VT[6] = p_[0];  VT[7] = p_[1]; \
    p_ = __builtin_amdgcn_cvt_pk_f32_fp8(CUR.z, false); VT[8] = p_[0];  VT[9] = p_[1]; \
    p_ = __builtin_amdgcn_cvt_pk_f32_fp8(CUR.z, true);  VT[10] = p_[0]; VT[11] = p_[1]; \
    p_ = __builtin_amdgcn_cvt_pk_f32_fp8(CUR.w, false); VT[12] = p_[0]; VT[13] = p_[1]; \
    p_ = __builtin_amdgcn_cvt_pk_f32_fp8(CUR.w, true);  VT[14] = p_[0]; VT[15] = p_[1]; }

    for (int iter = 0; iter < 3; ++iter) {
#pragma unroll
        for (int q = 0; q < 16; ++q) sreg[q] = 0.f;

        uint4 f0 = VROW(0), f1 = VROW(1), f2 = VROW(2), f3 = VROW(3);

#pragma unroll
        for (int s = 0; s < 9; ++s) {
            int i = (s << 5) + grp;
            uint4 cur = f0;
            f0 = f1; f1 = f2; f2 = f3;
            if (s + 4 < 9) f3 = VROW(s + 4);

            float vt[16];   // raw fp8-decoded (x32-scaled votes)
            DECODE(cur, vt);

            float cij;
            if (iter == 0) {
                cij = afs[i] * (1.0f / 32.0f);
            } else {
                float ah = 0.f;   // vt(raw) . vjr(pre-scaled) == true dot
#pragma unroll
                for (int q = 0; q < 16; ++q) ah += vt[q] * vjr[q];
                float e = __expf(ah);
                float ssum = e;
                ssum += __shfl_xor(ssum, 1);
                ssum += __shfl_xor(ssum, 2);
                ssum += __shfl_xor(ssum, 4);
                ssum += __shfl_xor(ssum, 8);
                ssum += __shfl_xor(ssum, 16);
                cij = e * __builtin_amdgcn_rcpf(ssum) * afs[i];
            }
#pragma unroll
            for (int q = 0; q < 16; ++q) sreg[q] += cij * vt[q];
        }

        // fold g-halves; wave wv's g=0 lanes write slot wv ([q*32+c]: bank==c)
#pragma unroll
        for (int q = 0; q < 16; ++q) sreg[q] += __shfl_xor(sreg[q], 32);
        if (g == 0) {
            float* sw = &sred[wv * CQ + c];
#pragma unroll
            for (int q = 0; q < 16; ++q) sw[q * 32] = sreg[q];
        }
        __syncthreads();
        if (t < CQ) {
            float ssum = 0.f;   // threads 0..511 == CQ columns, 16-slot fold
#pragma unroll
            for (int k = 0; k < RT_WAVES; ++k) ssum += sred[k * CQ + t];
            sred[t] = ssum * VINV;   // descale the x32 fp8 encoding ONCE
        }
        __syncthreads();

        // squash (threads 0..31, one c each; element (c,q) at sred[q*32+c])
        if (t < NC) {
            float s2 = 0.f;
#pragma unroll
            for (int q = 0; q < 16; ++q) {
                float s = sred[q * 32 + t];
                s2 += s * s;
            }
            float f = (s2 / (1.f + s2)) / sqrtf(s2 + EPSV);
            float vn2 = 0.f;
#pragma unroll
            for (int q = 0; q < 16; ++q) {
                float v = f * sred[q * 32 + t];
                vj[q * 32 + t] = v;
                vn2 += v * v;
            }
            if (iter == 2) {
                float ao = sqrtf(vn2 + EPSV);
                ao = fminf(fmaxf(ao, 1e-4f), 1.f - 1e-4f);
                aout_s[t] = ao;
            }
        }
        __syncthreads();
        if (iter < 2) {
#pragma unroll
            for (int q = 0; q < 16; ++q) {
                float v = vj[q * 32 + c] * VINV;   // pre-scale for the raw dot
                vjr[q] = (iter == 0) ? v : vjr[q] + v;
            }
        }
    }

    // outputs: p_out, a_out, concat(out).  canonical idx t: c=t>>4, q=t&15
    if (t < CQ) {
        float v = vj[(t & 15) * 32 + (t >> 4)];
        out[(size_t)n * CQ + t] = v;
        out[OFF_CAT + (size_t)n * 544 + t] = v;
    }
    if (t < NC) {
        float ao = aout_s[t];
        out[OFF_AOUT + n * 32 + t] = ao;
        out[OFF_CAT + (size_t)n * 544 + 512 + t] = ao;
    }
}

// ---------------------------------------------------------------------------
extern "C" void kernel_launch(void* const* d_in, const int* in_sizes, int n_in,
                              void* d_out, int out_size, void* d_ws, size_t ws_size,
                              hipStream_t stream) {
    const float* x = (const float*)d_in[0];
    const float* wts = (const float*)d_in[1];
    float* out = (float*)d_out;
    uchar* votes = (uchar*)d_ws;   // 57.8 MB fp8

    hipLaunchKernelGGL(votes_k, dim3(7, NI), dim3(256), 0, stream,
                       x, wts, votes);
    hipLaunchKernelGGL(routing_k, dim3(NB), dim3(RT_THREADS), 0, stream,
                       votes, x, out);
}

// Round 3
// 114.553 us; speedup vs baseline: 1.0840x; 1.0223x over previous
//
#include <hip/hip_runtime.h>
#include <hip/hip_fp16.h>
#include <math.h>

// Problem constants
#define NB 392      // n = b*oh*ow = 2*14*14
#define NI 288      // K*K*B = 9*32
#define NC 32       // C
#define NQ 16       // PSIZE
#define CQ 512      // NC*NQ
#define CH 544      // B*(PSIZE+1)
#define EPSV 1e-6f

// votes are fp8 e4m3 scaled by 32; scale folded into staged f16 weights
// (32 = 2^5, exact in f16 -> bitwise-identical products vs scaling after).
#define VSCALE 32.0f
#define VINV (1.0f / 32.0f)

// out layout (floats)
#define OFF_AOUT 200704       // NB*CQ
#define OFF_CAT  213248       // OFF_AOUT + NB*NC

#define RT_THREADS 512
#define RT_WAVES 8

typedef _Float16 v4h __attribute__((ext_vector_type(4)));
typedef float v4f __attribute__((ext_vector_type(4)));
typedef float v2f __attribute__((ext_vector_type(2)));

// ---------------------------------------------------------------------------
// Gather from x via the unfold channel-major reinterpret.
__device__ __forceinline__ float gather_x(const float* __restrict__ x, int n, int j) {
    int c_idx = j / 9;
    int rem = j - c_idx * 9;
    int ki = rem / 3;
    int kj = rem - ki * 3;
    int b_ = n / 196;
    int rest = n - b_ * 196;
    int yy = rest / 14;
    int xx = rest - yy * 14;
    int iy = yy + ki - 1;
    int ix = xx + kj - 1;
    float v = 0.f;
    if ((unsigned)iy < 14u && (unsigned)ix < 14u)
        v = x[((b_ * 14 + iy) * 14 + ix) * CH + c_idx];
    return v;
}

// ---------------------------------------------------------------------------
// votes via swapped-operand mfma 16x16x16 f16.
// ROUND-3 CHANGE: wts[i] is staged ONCE per block into LDS as f16 (x32
// pre-scaled), transposed + XOR-swizzled (s = (ct*4+quad)&15) so the
// B-fragment is a single conflict-free ds_read_b64. Replaces 128 scalar
// global_load_dword + 128 cvt + 128 mul per thread (4 waves each re-reading
// the full 32 KB through L1) with 8 dwordx4 + 32 ds_write_b16 staged once.
// Element (ct, qd, q, kk) -> wlds[ct*256 + qd*64 + ((q ^ ((ct*4+qd)&15))<<2) + kk]
//  - write side: per instr, bank = f(l&3, e^qd, kk>>1) covers 32 banks,
//    2 lanes/bank -> free.
//  - read side: b64, per 16-lane group col^s is a bijection -> at b64 floor.
__global__ __launch_bounds__(256) void votes_k(const float* __restrict__ x,
                                               const float* __restrict__ wts,
                                               uchar* __restrict__ votes) {
    __shared__ _Float16 wlds[8192];     // 16 KB swizzled f16 weights (x32)
    __shared__ uint tile[64 * 36];      // 9 KB, pitch 36 dwords (144 B)
    int mtt = blockIdx.x;         // 0..6
    int i = blockIdx.y;           // 0..287
    int t = threadIdx.x;
    int wv = t >> 6;
    int l = t & 63;
    int col = l & 15;
    int quad = l >> 4;

    // ---- stage wts[i] -> LDS (f16, x32, transposed, swizzled) ----
    const float* wsrc = wts + (size_t)i * 8192;
#pragma unroll
    for (int k = 0; k < 8; ++k) {
        int f0 = k * 1024 + t * 4;
        float4 w4 = *(const float4*)(wsrc + f0);
        int ct = f0 >> 8;
        int p = (f0 >> 4) & 15;
        int qd = p >> 2;
        int kk = p & 3;
        int q0 = f0 & 15;
        int s = (ct * 4 + qd) & 15;
        int base = ct * 256 + qd * 64 + kk;
        wlds[base + (((q0 + 0) ^ s) << 2)] = (_Float16)(w4.x * VSCALE);
        wlds[base + (((q0 + 1) ^ s) << 2)] = (_Float16)(w4.y * VSCALE);
        wlds[base + (((q0 + 2) ^ s) << 2)] = (_Float16)(w4.z * VSCALE);
        wlds[base + (((q0 + 3) ^ s) << 2)] = (_Float16)(w4.w * VSCALE);
    }

    // A-side p-frag: gather 4 p-values from x in-lane (n_row = col-mapped)
    int n_row = mtt * 64 + wv * 16 + col;
    v4h av = {};
    if (n_row < NB) {
        int jb = (i >> 5) * CH + (i & 31) * 16 + quad * 4;
#pragma unroll
        for (int kk = 0; kk < 4; ++kk)
            av[kk] = (_Float16)gather_x(x, n_row, jb + kk);
    }
    __syncthreads();

    const uchar* tileb = (const uchar*)tile;

    for (int ch = 0; ch < 4; ++ch) {
#pragma unroll
        for (int c8 = 0; c8 < 8; ++c8) {
            int ct = ch * 8 + c8;
            // bv: one conflict-free ds_read_b64 (weights pre-scaled x32)
            v4h bv = *(const v4h*)&wlds[ct * 256 + quad * 64 +
                                        ((col ^ ((ct * 4 + quad) & 15)) << 2)];
            v4f acc = {0.f, 0.f, 0.f, 0.f};
            acc = __builtin_amdgcn_mfma_f32_16x16x16f16(bv, av, acc, 0, 0, 0);
            // lane holds votes[n=...+col][cq = ct*16 + quad*4 + 0..3]
            uint u = __builtin_amdgcn_cvt_pk_fp8_f32(acc[0], acc[1], 0, false);
            u = __builtin_amdgcn_cvt_pk_fp8_f32(acc[2], acc[3], u, true);
            tile[(wv * 16 + col) * 36 + c8 * 4 + quad] = u;
        }
        __syncthreads();
        // 64 rows x 8 uint4 = 512 uint4; 2 steps; 8 lanes store a row's 128 B.
#pragma unroll
        for (int k = 0; k < 2; ++k) {
            int idx = k * 256 + t;
            int row = idx >> 3;
            int off = idx & 7;
            int n_out = mtt * 64 + row;
            if (n_out < NB) {
                uint4 d = *(const uint4*)&tileb[row * 144 + off * 16];
                *(uint4*)(votes + (((size_t)n_out * NI + i) << 9) + ch * 128 + off * 16) = d;
            }
        }
        __syncthreads();
    }
}

// ---------------------------------------------------------------------------
// Fused dynamic routing — REVERTED to the round-0 best-measured form:
// 512 threads (8 waves), i split 16-way, 18 steps, depth-4 global prefetch.
// (Rounds 1-2 showed routing is near its floor; both edits were <=+-2%.)
__global__ __launch_bounds__(RT_THREADS) void routing_k(const uchar* __restrict__ votes,
                                                        const float* __restrict__ x,
                                                        float* __restrict__ out) {
    __shared__ float afs[NI];
    __shared__ float sred[RT_WAVES * CQ];   // 16 KB, [group][q*32+c]
    __shared__ float vj[CQ];                // [q*32+c]
    __shared__ float aout_s[NC];

    int n = blockIdx.x;
    int t = threadIdx.x;
    int wv = t >> 6;      // 0..7
    int l = t & 63;
    int c = l & 31;
    int g = l >> 5;

    if (t < NI) {
        int j = (t >> 5) * CH + 512 + (t & 31);
        float v = gather_x(x, n, j);
        float a = fminf(fmaxf(v, 1e-4f), 1.0f);
        afs[t] = a / (a + EPSV);
    }
    __syncthreads();

    const uchar* vb = votes + (size_t)n * NI * 512;
    float vjr[16];    // cumulative vj, PRE-SCALED by 1/32
    float sreg[16];

#define VROW(S) (((const uint4*)(vb + ((size_t)(((((S) << 3) + wv) << 1) + g) << 9)))[c])

    for (int iter = 0; iter < 3; ++iter) {
#pragma unroll
        for (int q = 0; q < 16; ++q) sreg[q] = 0.f;

        uint4 f0 = VROW(0), f1 = VROW(1), f2 = VROW(2), f3 = VROW(3);

#pragma clang loop unroll_count(2)
        for (int s = 0; s < 18; ++s) {
            int i = ((s << 3) + wv) * 2 + g;
            uint4 cur = f0;
            f0 = f1; f1 = f2; f2 = f3;
            if (s + 4 < 18) f3 = VROW(s + 4);

            float vt[16];   // raw fp8-decoded (x32-scaled votes)
            {
                v2f p;
                p = __builtin_amdgcn_cvt_pk_f32_fp8(cur.x, false); vt[0] = p[0];  vt[1] = p[1];
                p = __builtin_amdgcn_cvt_pk_f32_fp8(cur.x, true);  vt[2] = p[0];  vt[3] = p[1];
                p = __builtin_amdgcn_cvt_pk_f32_fp8(cur.y, false); vt[4] = p[0];  vt[5] = p[1];
                p = __builtin_amdgcn_cvt_pk_f32_fp8(cur.y, true);  vt[6] = p[0];  vt[7] = p[1];
                p = __builtin_amdgcn_cvt_pk_f32_fp8(cur.z, false); vt[8] = p[0];  vt[9] = p[1];
                p = __builtin_amdgcn_cvt_pk_f32_fp8(cur.z, true);  vt[10] = p[0]; vt[11] = p[1];
                p = __builtin_amdgcn_cvt_pk_f32_fp8(cur.w, false); vt[12] = p[0]; vt[13] = p[1];
                p = __builtin_amdgcn_cvt_pk_f32_fp8(cur.w, true);  vt[14] = p[0]; vt[15] = p[1];
            }
            float cij;
            if (iter == 0) {
                cij = afs[i] * (1.0f / 32.0f);
            } else {
                float ah = 0.f;   // vt(raw) . vjr(pre-scaled) == true dot
#pragma unroll
                for (int q = 0; q < 16; ++q) ah += vt[q] * vjr[q];
                float e = __expf(ah);
                float ssum = e;
                ssum += __shfl_xor(ssum, 1);
                ssum += __shfl_xor(ssum, 2);
                ssum += __shfl_xor(ssum, 4);
                ssum += __shfl_xor(ssum, 8);
                ssum += __shfl_xor(ssum, 16);
                cij = e * __builtin_amdgcn_rcpf(ssum) * afs[i];
            }
#pragma unroll
            for (int q = 0; q < 16; ++q) sreg[q] += cij * vt[q];
        }

        // fold g-halves, write 8 partial groups (layout [q*32+c]: bank==c)
#pragma unroll
        for (int q = 0; q < 16; ++q) sreg[q] += __shfl_xor(sreg[q], 32);
        if (g == 0) {
            float* sw = &sred[wv * CQ + c];
#pragma unroll
            for (int q = 0; q < 16; ++q) sw[q * 32] = sreg[q];
        }
        __syncthreads();
        {
            float ssum = 0.f;   // 512 threads == CQ columns
#pragma unroll
            for (int k = 0; k < RT_WAVES; ++k) ssum += sred[k * CQ + t];
            sred[t] = ssum * VINV;   // descale the x32 fp8 encoding ONCE
        }
        __syncthreads();

        // squash (threads 0..31, one c each; element (c,q) at sred[q*32+c])
        if (t < NC) {
            float s2 = 0.f;
#pragma unroll
            for (int q = 0; q < 16; ++q) {
                float s = sred[q * 32 + t];
                s2 += s * s;
            }
            float f = (s2 / (1.f + s2)) / sqrtf(s2 + EPSV);
            float vn2 = 0.f;
#pragma unroll
            for (int q = 0; q < 16; ++q) {
                float v = f * sred[q * 32 + t];
                vj[q * 32 + t] = v;
                vn2 += v * v;
            }
            if (iter == 2) {
                float ao = sqrtf(vn2 + EPSV);
                ao = fminf(fmaxf(ao, 1e-4f), 1.f - 1e-4f);
                aout_s[t] = ao;
            }
        }
        __syncthreads();
        if (iter < 2) {
#pragma unroll
            for (int q = 0; q < 16; ++q) {
                float v = vj[q * 32 + c] * VINV;   // pre-scale for the raw dot
                vjr[q] = (iter == 0) ? v : vjr[q] + v;
            }
        }
    }

    // outputs: p_out, a_out, concat(out).  canonical idx t: c=t>>4, q=t&15
    {
        float v = vj[(t & 15) * 32 + (t >> 4)];
        out[(size_t)n * CQ + t] = v;
        out[OFF_CAT + (size_t)n * 544 + t] = v;
    }
    if (t < NC) {
        float ao = aout_s[t];
        out[OFF_AOUT + n * 32 + t] = ao;
        out[OFF_CAT + (size_t)n * 544 + 512 + t] = ao;
    }
}

// ---------------------------------------------------------------------------
extern "C" void kernel_launch(void* const* d_in, const int* in_sizes, int n_in,
                              void* d_out, int out_size, void* d_ws, size_t ws_size,
                              hipStream_t stream) {
    const float* x = (const float*)d_in[0];
    const float* wts = (const float*)d_in[1];
    float* out = (float*)d_out;
    uchar* votes = (uchar*)d_ws;   // 57.8 MB fp8

    hipLaunchKernelGGL(votes_k, dim3(7, NI), dim3(256), 0, stream,
                       x, wts, votes);
    hipLaunchKernelGGL(routing_k, dim3(NB), dim3(RT_THREADS), 0, stream,
                       votes, x, out);
}